// Round 1
// baseline (1106.943 us; speedup 1.0000x reference)
//
#include <hip/hip_runtime.h>
#include <cstdint>
#include <cstddef>

#define S_LEN 384
#define BATCH 256
#define DIM   192     // HH*WW
#define HID   100
#define G4    400     // 4*HID
#define NCLS  250

__device__ __forceinline__ float sigmoid_f(float v) {
    return 1.0f / (1.0f + __expf(-v));
}
__device__ __forceinline__ float tanh_f(float v) {
    // tanh(v) = 1 - 2/(exp(2v)+1); robust at +-inf
    float e = __expf(2.0f * v);
    return 1.0f - 2.0f / (e + 1.0f);
}

// ---------------------------------------------------------------------------
// Kernel 1: pre[rl][k] = sum_d x[b][s][d] * W[d][k] + bias[k]
//   rows rl = s_local*256 + b  (chunk-local), 64 rows per 1-wave block.
//   grid = (chunk*256/64, 4); blockIdx.y picks a 100-column slice.
//   lane = row; 100 fp32 accumulators per lane; W/bias addresses are
//   block-uniform -> compiler scalarizes to s_load (W operand in SGPRs),
//   inner loop is pure v_fma. No LDS at all.
// ---------------------------------------------------------------------------
__global__ __launch_bounds__(64, 2)
void gemm_pre(const float* __restrict__ x, const float* __restrict__ W,
              const float* __restrict__ bias, float* __restrict__ pre,
              int s_start)
{
    const int lane = threadIdx.x;
    const int rl   = blockIdx.x * 64 + lane;   // chunk-local row
    const int s    = s_start + (rl >> 8);      // rl / 256
    const int b    = rl & 255;
    const float* __restrict__ xrow = x + ((size_t)b * S_LEN + s) * DIM;
    const int cbase = blockIdx.y * 100;        // block-uniform
    const float* __restrict__ Wc = W + cbase;
    const float* __restrict__ bp = bias + cbase;

    float acc[100];
#pragma unroll
    for (int i = 0; i < 100; ++i) acc[i] = 0.0f;

    // prefetch first 16-k chunk of this row
    float4 xc0 = ((const float4*)xrow)[0];
    float4 xc1 = ((const float4*)xrow)[1];
    float4 xc2 = ((const float4*)xrow)[2];
    float4 xc3 = ((const float4*)xrow)[3];

    for (int kc = 0; kc < DIM; kc += 16) {
        float xr[16];
        xr[0]  = xc0.x; xr[1]  = xc0.y; xr[2]  = xc0.z; xr[3]  = xc0.w;
        xr[4]  = xc1.x; xr[5]  = xc1.y; xr[6]  = xc1.z; xr[7]  = xc1.w;
        xr[8]  = xc2.x; xr[9]  = xc2.y; xr[10] = xc2.z; xr[11] = xc2.w;
        xr[12] = xc3.x; xr[13] = xc3.y; xr[14] = xc3.z; xr[15] = xc3.w;
        if (kc + 16 < DIM) {   // prefetch next chunk while computing
            const float4* xp = (const float4*)(xrow + kc + 16);
            xc0 = xp[0]; xc1 = xp[1]; xc2 = xp[2]; xc3 = xp[3];
        }
#pragma unroll
        for (int kk = 0; kk < 16; ++kk) {
            const float* __restrict__ wrow = Wc + (size_t)(kc + kk) * G4;
#pragma unroll
            for (int c = 0; c < 100; ++c)
                acc[c] = fmaf(xr[kk], wrow[c], acc[c]);   // wrow[c]: s_load
        }
    }

    float* __restrict__ prow = pre + (size_t)rl * G4 + cbase;
#pragma unroll
    for (int c4 = 0; c4 < 25; ++c4) {
        float4 v;
        v.x = acc[4 * c4 + 0] + bp[4 * c4 + 0];
        v.y = acc[4 * c4 + 1] + bp[4 * c4 + 1];
        v.z = acc[4 * c4 + 2] + bp[4 * c4 + 2];
        v.w = acc[4 * c4 + 3] + bp[4 * c4 + 3];
        ((float4*)prow)[c4] = v;
    }
}

// ---------------------------------------------------------------------------
// Kernel 2: sequential LSTM scan. One block per batch element (grid=256).
//   Thread pair (n, q): q=0 owns gates (i,f) of h-element n, q=1 owns (g,o).
//   Each thread holds its two U columns (2*100 fp32) in REGISTERS.
//   h lives in LDS, double-buffered; broadcast ds_read_b128 per step.
//   Gate exchange via __shfl_xor(...,1) (adjacent lanes, same wave).
//   c stays in registers. One __syncthreads per step.
//   Epilogue: last chunk computes out[b][:] = hT @ Wd + bd.
// ---------------------------------------------------------------------------
__global__ __launch_bounds__(256, 1)
void lstm_scan(const float* __restrict__ pre, const float* __restrict__ U,
               const float* __restrict__ Wd, const float* __restrict__ bd,
               float* __restrict__ out, float* __restrict__ state,
               int nsteps, int first, int last)
{
    __shared__ float hbuf[2][HID];
    const int b = blockIdx.x;
    const int t = threadIdx.x;
    const int q = t & 1;
    int n = t >> 1;
    if (n > HID - 1) n = HID - 1;              // clamp idle lanes to valid addrs
    const bool wlane = (t < 2 * HID) && (q == 0);

    // Keras gate order i,f,g,o: q=0 -> {n, 100+n}; q=1 -> {200+n, 300+n}
    const int k0 = q * 200 + n;
    const int k1 = q * 200 + 100 + n;

    float Ur0[HID], Ur1[HID];
#pragma unroll
    for (int j = 0; j < HID; ++j) {
        Ur0[j] = U[(size_t)j * G4 + k0];
        Ur1[j] = U[(size_t)j * G4 + k1];
    }

    float c;
    if (first) {
        c = 0.0f;
        if (t < HID) hbuf[0][t] = 0.0f;
    } else {
        c = state[BATCH * HID + b * HID + n];
        if (t < HID) hbuf[0][t] = state[b * HID + t];
    }
    __syncthreads();

    // prefetch step 0 preactivations
    const float* __restrict__ pb0 = pre + (size_t)b * G4;
    float z0 = pb0[k0];
    float z1 = pb0[k1];

    for (int s = 0; s < nsteps; ++s) {
        const int cur = s & 1;
        const float4* __restrict__ hb4 = (const float4*)hbuf[cur];
        float a0 = z0, a1 = z1;
        float a0b = 0.0f, a1b = 0.0f;

        if (s + 1 < nsteps) {   // prefetch next step's pre during FMAs
            const float* __restrict__ pn = pre + ((size_t)(s + 1) * BATCH + b) * G4;
            z0 = pn[k0];
            z1 = pn[k1];
        }

#pragma unroll
        for (int j4 = 0; j4 < HID / 4; ++j4) {
            float4 hv = hb4[j4];                       // broadcast LDS read
            a0  = fmaf(Ur0[4 * j4 + 0], hv.x, a0);
            a0b = fmaf(Ur0[4 * j4 + 1], hv.y, a0b);
            a0  = fmaf(Ur0[4 * j4 + 2], hv.z, a0);
            a0b = fmaf(Ur0[4 * j4 + 3], hv.w, a0b);
            a1  = fmaf(Ur1[4 * j4 + 0], hv.x, a1);
            a1b = fmaf(Ur1[4 * j4 + 1], hv.y, a1b);
            a1  = fmaf(Ur1[4 * j4 + 2], hv.z, a1);
            a1b = fmaf(Ur1[4 * j4 + 3], hv.w, a1b);
        }
        a0 += a0b;
        a1 += a1b;

        float v0, v1;
        if (q == 0) { v0 = sigmoid_f(a0); v1 = sigmoid_f(a1); }   // i, f
        else        { v0 = tanh_f(a0);    v1 = sigmoid_f(a1); }   // g, o
        float p0 = __shfl_xor(v0, 1);
        float p1 = __shfl_xor(v1, 1);
        float gi = (q == 0) ? v0 : p0;
        float gf = (q == 0) ? v1 : p1;
        float gg = (q == 0) ? p0 : v0;
        float go = (q == 0) ? p1 : v1;

        c = fmaf(gf, c, gi * gg);
        float hn = go * tanh_f(c);
        if (wlane) hbuf[cur ^ 1][n] = hn;
        __syncthreads();
    }

    const float* __restrict__ hf = hbuf[nsteps & 1];
    if (last) {
        // out[b][t] = bd[t] + sum_j hT[j] * Wd[j][t]   (coalesced over t)
        if (t < NCLS) {
            float acc = bd[t];
#pragma unroll 5
            for (int j = 0; j < HID; ++j)
                acc = fmaf(hf[j], Wd[(size_t)j * NCLS + t], acc);
            out[(size_t)b * NCLS + t] = acc;
        }
    } else {
        if (t < HID) state[b * HID + t] = hf[t];
        if (wlane) state[BATCH * HID + b * HID + n] = c;
    }
}

// ---------------------------------------------------------------------------
extern "C" void kernel_launch(void* const* d_in, const int* in_sizes, int n_in,
                              void* d_out, int out_size, void* d_ws, size_t ws_size,
                              hipStream_t stream)
{
    const float* x    = (const float*)d_in[0];
    const float* W    = (const float*)d_in[1];
    const float* U    = (const float*)d_in[2];
    const float* bias = (const float*)d_in[3];
    const float* Wd   = (const float*)d_in[4];
    const float* bd   = (const float*)d_in[5];
    float* out = (float*)d_out;

    // ws layout: [state: h(256*100) + c(256*100)] [pre chunk: chunk*256*400]
    const size_t state_floats = (size_t)2 * BATCH * HID;
    int nchunks = 1;
    while (nchunks < S_LEN) {
        size_t need = ((size_t)(S_LEN / nchunks) * BATCH * G4 + state_floats) * sizeof(float);
        if (need <= ws_size) break;
        nchunks *= 2;
    }
    const int chunk = S_LEN / nchunks;
    float* state = (float*)d_ws;
    float* pre   = state + state_floats;

    for (int ci = 0; ci < nchunks; ++ci) {
        const int s0 = ci * chunk;
        dim3 g1((chunk * BATCH) / 64, 4);
        gemm_pre<<<g1, 64, 0, stream>>>(x, W, bias, pre, s0);
        lstm_scan<<<BATCH, 256, 0, stream>>>(pre, U, Wd, bd, out, state,
                                             chunk, ci == 0 ? 1 : 0,
                                             ci == nchunks - 1 ? 1 : 0);
    }
}

// Round 2
// 737.630 us; speedup vs baseline: 1.5007x; 1.5007x over previous
//
#include <hip/hip_runtime.h>
#include <cstdint>
#include <cstddef>

#define S_LEN 384
#define BATCH 256
#define DIM   192     // HH*WW
#define HID   100
#define G4    400     // 4*HID
#define NCLS  250

#define LOG2E  1.4426950408889634f
#define LOG2E2 2.8853900817779268f

// ---------------------------------------------------------------------------
// Kernel 1: pre[rl][k] = sum_d x[b][s][d] * W[d][k] + bias[k]
//   lane = row, 50 columns of accumulators per lane (grid.y = 8 slices).
//   W/bias addresses are block-uniform -> s_load (W operand in SGPRs).
//   50 acc + 16 xr + 16 prefetch ~ 95 VGPR: no spill (round-1's acc[100]
//   spilled at VGPR_Count=88 -> 653us, VALUBusy 15%).
// ---------------------------------------------------------------------------
__global__ __launch_bounds__(64, 4)
void gemm_pre(const float* __restrict__ x, const float* __restrict__ W,
              const float* __restrict__ bias, float* __restrict__ pre,
              int s_start)
{
    const int lane = threadIdx.x;
    const int rl   = blockIdx.x * 64 + lane;   // chunk-local row
    const int s    = s_start + (rl >> 8);      // rl / 256
    const int b    = rl & 255;
    const float* __restrict__ xrow = x + ((size_t)b * S_LEN + s) * DIM;
    const int cbase = blockIdx.y * 50;         // block-uniform
    const float* __restrict__ Wc = W + cbase;
    const float* __restrict__ bp = bias + cbase;

    float acc[50];
#pragma unroll
    for (int i = 0; i < 50; ++i) acc[i] = 0.0f;

    float4 xc0 = ((const float4*)xrow)[0];
    float4 xc1 = ((const float4*)xrow)[1];
    float4 xc2 = ((const float4*)xrow)[2];
    float4 xc3 = ((const float4*)xrow)[3];

    for (int kc = 0; kc < DIM; kc += 16) {
        float xr[16];
        xr[0]  = xc0.x; xr[1]  = xc0.y; xr[2]  = xc0.z; xr[3]  = xc0.w;
        xr[4]  = xc1.x; xr[5]  = xc1.y; xr[6]  = xc1.z; xr[7]  = xc1.w;
        xr[8]  = xc2.x; xr[9]  = xc2.y; xr[10] = xc2.z; xr[11] = xc2.w;
        xr[12] = xc3.x; xr[13] = xc3.y; xr[14] = xc3.z; xr[15] = xc3.w;
        if (kc + 16 < DIM) {   // prefetch next chunk while computing
            const float4* xp = (const float4*)(xrow + kc + 16);
            xc0 = xp[0]; xc1 = xp[1]; xc2 = xp[2]; xc3 = xp[3];
        }
#pragma unroll
        for (int kk = 0; kk < 16; ++kk) {
            const float* __restrict__ wrow = Wc + (size_t)(kc + kk) * G4;
#pragma unroll
            for (int c = 0; c < 50; ++c)
                acc[c] = fmaf(xr[kk], wrow[c], acc[c]);   // wrow[c]: s_load
        }
    }

    // cbase*4 = y*200 bytes: only 8B-aligned for odd y -> float2 stores
    float* __restrict__ prow = pre + (size_t)rl * G4 + cbase;
#pragma unroll
    for (int c2 = 0; c2 < 25; ++c2) {
        float2 v;
        v.x = acc[2 * c2 + 0] + bp[2 * c2 + 0];
        v.y = acc[2 * c2 + 1] + bp[2 * c2 + 1];
        ((float2*)prow)[c2] = v;
    }
}

// ---------------------------------------------------------------------------
// Kernel 2: sequential LSTM scan. One block (512 thr, 8 waves = 2/SIMD) per
//   batch element. Thread t: unit n = t>>2 (clamped <100), gate g = t&3
//   (Keras order i,f,g,o). All 4 gates of a unit live in one QUAD of one
//   wave -> gate combine via 3 __shfl_xor (DPP quad_perm), no LDS exchange,
//   ONE barrier per step. Each thread holds its U column (100 fp32) in regs.
//   c replicated across the quad. Activations: branchless sigmoid/tanh via
//   v_exp_f32 + v_rcp_f32 (no full-precision divides).
// ---------------------------------------------------------------------------
__global__ __launch_bounds__(512, 2)
void lstm_scan(const float* __restrict__ pre, const float* __restrict__ U,
               const float* __restrict__ Wd, const float* __restrict__ bd,
               float* __restrict__ out, float* __restrict__ state,
               int nsteps, int first, int last)
{
    __shared__ float hbuf[2][HID];
    const int b  = blockIdx.x;
    const int t  = threadIdx.x;
    const int g  = t & 3;
    const int nr = t >> 2;                 // 0..127
    const int n  = (nr < HID) ? nr : HID - 1;
    const bool wlane = (g == 0) && (nr < HID);
    const int col = g * HID + n;           // gate column in [0,400)

    // unified activation: v = A*rcp(1+exp2(scale*a)) + B
    //   sigmoid(a) = rcp(1+exp2(-log2e*a));  tanh(a) = 2*sigmoid(2a)-1
    const float scale = (g == 2) ? -LOG2E2 : -LOG2E;
    const float Aact  = (g == 2) ? 2.0f : 1.0f;
    const float Bact  = (g == 2) ? -1.0f : 0.0f;

    float Uc[HID];
#pragma unroll
    for (int j = 0; j < HID; ++j)
        Uc[j] = U[(size_t)j * G4 + col];

    float c = 0.0f;
    if (first) {
        if (t < HID) hbuf[0][t] = 0.0f;
    } else {
        if (t < HID) hbuf[0][t] = state[b * HID + t];
        c = state[BATCH * HID + b * HID + n];   // replicated per quad
    }
    __syncthreads();

    float z = pre[(size_t)b * G4 + col];   // step-0 preactivation

    for (int s = 0; s < nsteps; ++s) {
        const int cur = s & 1;
        float a = z, a2 = 0.0f, a3 = 0.0f, a4 = 0.0f;
        if (s + 1 < nsteps)                 // prefetch next step (L3-resident)
            z = pre[((size_t)(s + 1) * BATCH + b) * G4 + col];

        const float4* __restrict__ h4 = (const float4*)hbuf[cur];
#pragma unroll
        for (int j4 = 0; j4 < HID / 4; ++j4) {
            float4 hv = h4[j4];                       // broadcast LDS read
            a  = fmaf(Uc[4 * j4 + 0], hv.x, a);
            a2 = fmaf(Uc[4 * j4 + 1], hv.y, a2);
            a3 = fmaf(Uc[4 * j4 + 2], hv.z, a3);
            a4 = fmaf(Uc[4 * j4 + 3], hv.w, a4);
        }
        a = (a + a2) + (a3 + a4);

        // own activated gate value
        float e = __builtin_amdgcn_exp2f(scale * a);
        float v = fmaf(Aact, __builtin_amdgcn_rcpf(1.0f + e), Bact);

        // quad exchange: p1 = lane g^1, p2 = lane g^2, p3 = lane g^3
        float p1 = __shfl_xor(v, 1);
        float p2 = __shfl_xor(v, 2);
        float p3 = __shfl_xor(p1, 2);
        const bool b0 = g & 1, b1 = g & 2;
        float xi = b1 ? (b0 ? p3 : p2) : (b0 ? p1 : v);
        float xf = b1 ? (b0 ? p2 : p3) : (b0 ? v  : p1);
        float xg = b1 ? (b0 ? p1 : v ) : (b0 ? p3 : p2);
        float xo = b1 ? (b0 ? v  : p1) : (b0 ? p2 : p3);

        c = fmaf(xf, c, xi * xg);          // replicated (identical) per quad
        float ec = __builtin_amdgcn_exp2f(-LOG2E2 * c);
        float tc = fmaf(2.0f, __builtin_amdgcn_rcpf(1.0f + ec), -1.0f);
        if (wlane) hbuf[cur ^ 1][n] = xo * tc;
        __syncthreads();
    }

    const float* __restrict__ hf = hbuf[nsteps & 1];
    if (last) {
        if (t < NCLS) {
            float acc = bd[t];
#pragma unroll 5
            for (int j = 0; j < HID; ++j)
                acc = fmaf(hf[j], Wd[(size_t)j * NCLS + t], acc);  // coalesced
            out[(size_t)b * NCLS + t] = acc;
        }
    } else {
        if (t < HID) state[b * HID + t] = hf[t];
        if (wlane) state[BATCH * HID + b * HID + n] = c;
    }
}

// ---------------------------------------------------------------------------
extern "C" void kernel_launch(void* const* d_in, const int* in_sizes, int n_in,
                              void* d_out, int out_size, void* d_ws, size_t ws_size,
                              hipStream_t stream)
{
    const float* x    = (const float*)d_in[0];
    const float* W    = (const float*)d_in[1];
    const float* U    = (const float*)d_in[2];
    const float* bias = (const float*)d_in[3];
    const float* Wd   = (const float*)d_in[4];
    const float* bd   = (const float*)d_in[5];
    float* out = (float*)d_out;

    // ws layout: [state: h(256*100) + c(256*100)] [pre chunk: chunk*256*400]
    const size_t state_floats = (size_t)2 * BATCH * HID;
    int nchunks = 1;
    while (nchunks < S_LEN) {
        size_t need = ((size_t)(S_LEN / nchunks) * BATCH * G4 + state_floats) * sizeof(float);
        if (need <= ws_size) break;
        nchunks *= 2;
    }
    const int chunk = S_LEN / nchunks;
    float* state = (float*)d_ws;
    float* pre   = state + state_floats;

    for (int ci = 0; ci < nchunks; ++ci) {
        const int s0 = ci * chunk;
        dim3 g1((chunk * BATCH) / 64, 8);
        gemm_pre<<<g1, 64, 0, stream>>>(x, W, bias, pre, s0);
        lstm_scan<<<BATCH, 512, 0, stream>>>(pre, U, Wd, bd, out, state,
                                             chunk, ci == 0 ? 1 : 0,
                                             ci == nchunks - 1 ? 1 : 0);
    }
}

// Round 3
// 694.326 us; speedup vs baseline: 1.5943x; 1.0624x over previous
//
#include <hip/hip_runtime.h>
#include <cstdint>
#include <cstddef>

#define S_LEN 384
#define BATCH 256
#define DIM   192     // HH*WW
#define HID   100
#define G4    400     // 4*HID
#define NCLS  250
#define KC    48      // gemm k-chunk staged in LDS

#define LOG2E  1.4426950408889634f
#define LOG2E2 2.8853900817779268f

// ---------------------------------------------------------------------------
// Kernel 1: pre[b][k][sl] = sum_d x[b][s][d] * W[d][k] + bias[k]
//   pre layout is k-major with s innermost (stride sstride) so that
//   (a) gemm stores are 64-lane-consecutive coalesced along s, and
//   (b) the scan reads its own column as a contiguous s-stream (float4/4 steps).
//   Block = 256 thr (4 waves) = 64 s-rows of ONE b; wave w -> 25-col group.
//   x staged via LDS (coalesced global loads; pad-49 row stride -> 2-way
//   bank aliasing = free). W/bias read at wave-uniform addresses -> s_load,
//   inner loop is v_fma with the W operand in SGPRs. 25 accs: no spill
//   (round-2's acc[50] went to AGPR/scratch: VGPR_Count=56, +100MB writes).
// ---------------------------------------------------------------------------
__global__ __launch_bounds__(256, 6)
void gemm_pre(const float* __restrict__ x, const float* __restrict__ W,
              const float* __restrict__ bias, float* __restrict__ pre,
              int s_start, int chunk)
{
    __shared__ float xl[64 * 49];          // 12.25 KB, pad 49: 2-way = free

    const int t    = threadIdx.x;
    const int lane = t & 63;
    const int nsb  = chunk >> 6;           // s-blocks per b
    const int bidx = blockIdx.x;
    const int b    = bidx / nsb;
    const int sblk = bidx - b * nsb;
    const int s0g  = s_start + sblk * 64;  // global s base of this block
    const int s0l  = sblk * 64;            // chunk-local s base
    const int w    = __builtin_amdgcn_readfirstlane(t >> 6);
    const int cbase = blockIdx.y * 100 + w * 25;   // wave-uniform
    const float* __restrict__ Wc = W + cbase;
    const float* __restrict__ bp = bias + cbase;
    const float* __restrict__ xb = x + ((size_t)b * S_LEN + s0g) * DIM;

    float acc[25];
#pragma unroll
    for (int i = 0; i < 25; ++i) acc[i] = 0.0f;

    for (int kc = 0; kc < DIM; kc += KC) {
        // ---- stage x[64 rows][KC floats] into LDS (coalesced) ----
        __syncthreads();                   // protect prev chunk's readers
#pragma unroll
        for (int r = 0; r < 3; ++r) {
            const int l   = t + r * 256;   // 0..767 : 64 rows x 12 float4
            const int row = l / 12;
            const int f4  = l - row * 12;
            float4 v = *(const float4*)(xb + (size_t)row * DIM + kc + f4 * 4);
            const int ba = row * 49 + f4 * 4;
            xl[ba + 0] = v.x; xl[ba + 1] = v.y;
            xl[ba + 2] = v.z; xl[ba + 3] = v.w;
        }
        __syncthreads();

        // ---- FMA: 25 cols per thread, W from SGPRs ----
        const float* __restrict__ xr = xl + lane * 49;
#pragma unroll 4
        for (int j = 0; j < KC; ++j) {
            const float xv = xr[j];
            const float* __restrict__ wr = Wc + (size_t)(kc + j) * G4;
#pragma unroll
            for (int c = 0; c < 25; ++c)
                acc[c] = fmaf(xv, wr[c], acc[c]);
        }
    }

    // ---- store: per c, 64 lanes write consecutive s -> coalesced 256B ----
    float* __restrict__ pp = pre + (size_t)b * G4 * chunk + s0l + lane;
#pragma unroll
    for (int c = 0; c < 25; ++c)
        pp[(size_t)(cbase + c) * chunk] = acc[c] + bp[c];
}

// ---------------------------------------------------------------------------
// Kernel 2: sequential LSTM scan. One block (512 thr, 8 waves) per batch b.
//   Thread t: unit n = t>>2 (active n<100), gate g = t&3 (Keras i,f,g,o).
//   All 4 gates of a unit in one QUAD -> combine via 3 __shfl_xor, no LDS
//   exchange, ONE barrier/step. U column (100 fp32) in registers.
//   pre stream is contiguous in s (layout [b][k][s]): ONE float4 load per
//   4 steps with 8-step lookahead -> the barrier's vmcnt(0) drain costs
//   ~L3 latency once per 4 steps instead of every step (round-2: every step).
// ---------------------------------------------------------------------------
__global__ __launch_bounds__(512, 2)
void lstm_scan(const float* __restrict__ pre, const float* __restrict__ U,
               const float* __restrict__ Wd, const float* __restrict__ bd,
               float* __restrict__ out, float* __restrict__ state,
               int nsteps, int first, int last)
{
    __shared__ float hbuf[2][HID];
    const int b  = blockIdx.x;
    const int t  = threadIdx.x;
    const int g  = t & 3;
    const int nr = t >> 2;                 // 0..127
    const int n  = (nr < HID) ? nr : HID - 1;
    const bool wlane = (g == 0) && (nr < HID);
    const int col = g * HID + n;           // gate column in [0,400)

    // unified activation: v = A*rcp(1+exp2(scale*a)) + B
    const float scale = (g == 2) ? -LOG2E2 : -LOG2E;
    const float Aact  = (g == 2) ? 2.0f : 1.0f;
    const float Bact  = (g == 2) ? -1.0f : 0.0f;

    float Uc[HID];
#pragma unroll
    for (int j = 0; j < HID; ++j)
        Uc[j] = U[(size_t)j * G4 + col];

    float c = 0.0f;
    if (first) {
        if (t < HID) hbuf[0][t] = 0.0f;
    } else {
        if (t < HID) hbuf[0][t] = state[b * HID + t];
        c = state[BATCH * HID + b * HID + n];   // replicated per quad
    }
    __syncthreads();

    // contiguous per-thread pre stream
    const float* __restrict__ zp = pre + ((size_t)b * G4 + col) * nsteps;
    float4 zA = *(const float4*)(zp);          // steps 0..3
    float4 zB = *(const float4*)(zp + 4);      // steps 4..7

    auto step = [&](float zin, int cur) {
        float a = zin, a2 = 0.0f, a3 = 0.0f, a4 = 0.0f;
        const float4* __restrict__ h4 = (const float4*)hbuf[cur];
#pragma unroll
        for (int j4 = 0; j4 < HID / 4; ++j4) {
            float4 hv = h4[j4];                // broadcast LDS read
            a  = fmaf(Uc[4 * j4 + 0], hv.x, a);
            a2 = fmaf(Uc[4 * j4 + 1], hv.y, a2);
            a3 = fmaf(Uc[4 * j4 + 2], hv.z, a3);
            a4 = fmaf(Uc[4 * j4 + 3], hv.w, a4);
        }
        a = (a + a2) + (a3 + a4);

        float e = __builtin_amdgcn_exp2f(scale * a);
        float v = fmaf(Aact, __builtin_amdgcn_rcpf(1.0f + e), Bact);

        float p1 = __shfl_xor(v, 1);
        float p2 = __shfl_xor(v, 2);
        float p3 = __shfl_xor(p1, 2);
        const bool b0 = g & 1, b1 = g & 2;
        float xi = b1 ? (b0 ? p3 : p2) : (b0 ? p1 : v);
        float xf = b1 ? (b0 ? p2 : p3) : (b0 ? v  : p1);
        float xg = b1 ? (b0 ? p1 : v ) : (b0 ? p3 : p2);
        float xo = b1 ? (b0 ? v  : p1) : (b0 ? p2 : p3);

        c = fmaf(xf, c, xi * xg);
        float ec = __builtin_amdgcn_exp2f(-LOG2E2 * c);
        float tc = fmaf(2.0f, __builtin_amdgcn_rcpf(1.0f + ec), -1.0f);
        if (wlane) hbuf[cur ^ 1][n] = xo * tc;
        __syncthreads();
    };

    for (int s4 = 0; s4 < nsteps; s4 += 4) {   // nsteps % 4 == 0
        float4 zn = zA; zA = zB;
        if (s4 + 8 < nsteps)
            zB = *(const float4*)(zp + s4 + 8);
        step(zn.x, 0);
        step(zn.y, 1);
        step(zn.z, 0);
        step(zn.w, 1);
    }

    const float* __restrict__ hf = hbuf[nsteps & 1];
    if (last) {
        if (t < NCLS) {
            float acc = bd[t];
#pragma unroll 5
            for (int j = 0; j < HID; ++j)
                acc = fmaf(hf[j], Wd[(size_t)j * NCLS + t], acc);  // coalesced
            out[(size_t)b * NCLS + t] = acc;
        }
    } else {
        if (t < HID) state[b * HID + t] = hf[t];
        if (wlane) state[BATCH * HID + b * HID + n] = c;
    }
}

// ---------------------------------------------------------------------------
extern "C" void kernel_launch(void* const* d_in, const int* in_sizes, int n_in,
                              void* d_out, int out_size, void* d_ws, size_t ws_size,
                              hipStream_t stream)
{
    const float* x    = (const float*)d_in[0];
    const float* W    = (const float*)d_in[1];
    const float* U    = (const float*)d_in[2];
    const float* bias = (const float*)d_in[3];
    const float* Wd   = (const float*)d_in[4];
    const float* bd   = (const float*)d_in[5];
    float* out = (float*)d_out;

    // ws: [state: h(256*100)+c(256*100)] [pre chunk: 256*400*chunk], chunk%64==0
    const size_t state_f = (size_t)2 * BATCH * HID;
    const size_t full    = (size_t)S_LEN * BATCH * G4;
    int chunk;
    if      (ws_size >= (full     + state_f) * 4) chunk = 384;
    else if (ws_size >= (full / 2 + state_f) * 4) chunk = 192;
    else                                          chunk = 64;
    const int nchunks = S_LEN / chunk;

    float* state = (float*)d_ws;
    float* pre   = state + state_f;

    for (int ci = 0; ci < nchunks; ++ci) {
        const int s0 = ci * chunk;
        dim3 g1(BATCH * (chunk >> 6), 4);
        gemm_pre<<<g1, 256, 0, stream>>>(x, W, bias, pre, s0, chunk);
        lstm_scan<<<BATCH, 512, 0, stream>>>(pre, U, Wd, bd, out, state,
                                             chunk, ci == 0 ? 1 : 0,
                                             ci == nchunks - 1 ? 1 : 0);
    }
}

// Round 6
// 386.313 us; speedup vs baseline: 2.8654x; 1.7973x over previous
//
#include <hip/hip_runtime.h>
#include <cstdint>
#include <cstddef>

#define S_LEN 384
#define BATCH 256
#define DIM   192     // HH*WW
#define HID   100
#define G4    400     // 4*HID
#define NCLS  250

#define LOG2E  1.4426950408889634f
#define LOG2E2 2.8853900817779268f

typedef float  f32x4  __attribute__((ext_vector_type(4)));
typedef short  bf16x8 __attribute__((ext_vector_type(8)));

static __device__ __forceinline__ unsigned short f2bf(float f) {
    unsigned u = __float_as_uint(f);
    return (unsigned short)((u + 0x7FFFu + ((u >> 16) & 1u)) >> 16);   // RN
}

// ---------------------------------------------------------------------------
// Prep A: Wt_bf[k=400][d=192] bf16  =  W[d][k] transposed+cast
// ---------------------------------------------------------------------------
__global__ void wprep(const float* __restrict__ W, unsigned short* __restrict__ Wt) {
    int i = blockIdx.x * 256 + threadIdx.x;          // 76800 elements
    if (i >= G4 * DIM) return;
    int k = i / DIM, d = i - k * DIM;
    Wt[i] = f2bf(W[(size_t)d * G4 + k]);
}

// ---------------------------------------------------------------------------
// Prep B: Ut[col=400][4 slices x 28] fp32 = U^T with j padded per 26-slice
//   Ut[col*112 + jg*28 + m] = U[26*jg+m][col]  (m<26, j<100), else 0.
// ---------------------------------------------------------------------------
__global__ void uprep(const float* __restrict__ U, float* __restrict__ Ut) {
    int i = blockIdx.x * 256 + threadIdx.x;          // 400*112 = 44800
    if (i >= G4 * 112) return;
    int col = i / 112, r = i - col * 112;
    int jg = r / 28, m = r - jg * 28;
    int j = 26 * jg + m;
    Ut[i] = (m < 26 && j < HID) ? U[(size_t)j * G4 + col] : 0.0f;
}

// ---------------------------------------------------------------------------
// Kernel 1: bf16 MFMA GEMM  pre[b][k][s] = x[b][s][:] . W[:][k]  (bias in scan)
//   Block = 256 thr (4 waves) = 64 s-rows of one b, all 400 k, K=192.
//   mfma_f32_16x16x32_bf16 (m89/m92-verified layouts):
//     A[m=lane&15][k=quad*8+j]  B[k=quad*8+j][n=lane&15] (B^T storage)
//     D: col(n)=lane&15, row(m)=quad*4+reg -> 4 acc regs = 4 consecutive s.
//   ROUND-6 FIX: W chunk row = 32 bf16 = 64 B = 4 x uint4. Rounds 4/5 staged
//   4 x uint2 (16 bf16) -> shorts 16..31 of every wsh row were UNINIT LDS ->
//   NaN bf16 patterns fed the q=2,3 fragments -> NaN out.
// ---------------------------------------------------------------------------
__global__ __launch_bounds__(256, 2)
void gemm_pre(const float* __restrict__ x, const unsigned short* __restrict__ Wt,
              float* __restrict__ pre, int s_start, int chunk)
{
    __shared__ unsigned int xs[64 * 100];    // rows: 200 bf16 (192 + 8 pad)
    __shared__ unsigned int wsh[400 * 20];   // rows: 40 bf16 (32 + 8 pad)

    const int t    = threadIdx.x;
    const int lane = t & 63;
    const int w    = t >> 6;
    const int nsb  = chunk >> 6;
    const int b    = blockIdx.x / nsb;
    const int sblk = blockIdx.x - b * nsb;
    const float* __restrict__ xb = x + ((size_t)b * S_LEN + s_start + sblk * 64) * DIM;

#pragma unroll
    for (int r = 0; r < 12; ++r) {
        int i = t + r * 256;                 // 3072 float4 = 64 rows x 48
        int row = i / 48, c4 = i - row * 48;
        float4 v = ((const float4*)(xb + (size_t)row * DIM))[c4];
        xs[row * 100 + c4 * 2]     = (unsigned)f2bf(v.x) | ((unsigned)f2bf(v.y) << 16);
        xs[row * 100 + c4 * 2 + 1] = (unsigned)f2bf(v.z) | ((unsigned)f2bf(v.w) << 16);
    }

    f32x4 acc[25];
#pragma unroll
    for (int ct = 0; ct < 25; ++ct) acc[ct] = (f32x4){0.f, 0.f, 0.f, 0.f};

    const int m = lane & 15, q = lane >> 4;

    for (int dc = 0; dc < 6; ++dc) {
        if (dc) __syncthreads();             // protect previous chunk's readers
#pragma unroll
        for (int r = 0; r < 7; ++r) {
            int i = t + r * 256;
            if (i < 1600) {                  // 400 rows x 4 uint4 (32 bf16 = 64B)
                int k = i >> 2, u4 = i & 3;
                uint4 v = *(const uint4*)(Wt + (size_t)k * DIM + dc * 32 + u4 * 8);
                *(uint4*)(wsh + k * 20 + u4 * 4) = v;
            }
        }
        __syncthreads();

        const unsigned short* xp = (const unsigned short*)xs
                                   + (16 * w + m) * 200 + dc * 32 + q * 8;
        bf16x8 af = *(const bf16x8*)xp;
#pragma unroll
        for (int ct = 0; ct < 25; ++ct) {
            const unsigned short* bp = (const unsigned short*)wsh
                                       + (ct * 16 + m) * 40 + q * 8;
            bf16x8 bf = *(const bf16x8*)bp;
            acc[ct] = __builtin_amdgcn_mfma_f32_16x16x32_bf16(af, bf, acc[ct], 0, 0, 0);
        }
    }

    float* __restrict__ pb = pre + (size_t)b * G4 * chunk + (size_t)sblk * 64
                             + 16 * w + q * 4;
#pragma unroll
    for (int ct = 0; ct < 25; ++ct) {
        float4 v = {acc[ct][0], acc[ct][1], acc[ct][2], acc[ct][3]};
        *(float4*)(pb + (size_t)(ct * 16 + m) * chunk) = v;
    }
}

// ---------------------------------------------------------------------------
// Kernel 2: LSTM scan, factorized, pure fp32. Block = 448 thr (7 waves) per b.
//   Thread (n = t>>2, jg = t&3):
//     - Ur[4][26] fp32 in regs: U[j in 26jg..+26)][all 4 gate cols of unit n]
//     - reads 26 fp32 of h from LDS per step (slice stride 28: the 4 slice
//       streams hit disjoint bank groups -> conflict-free broadcast)
//     - 104 fmaf -> 4 partials; quad transpose-reduce (shfl_xor 1,2) ->
//       thread owns gate jg of unit n; activation; quad gate-combine;
//       replicated c; ONE barrier/step.
//   pre stream contiguous in s ([b][k][s]): float4 per 4 steps, 8-step ahead.
// ---------------------------------------------------------------------------
__global__ __launch_bounds__(448)
void lstm_scan(const float* __restrict__ pre, const float* __restrict__ Ut,
               const float* __restrict__ bias, const float* __restrict__ Wd,
               const float* __restrict__ bd, float* __restrict__ out,
               float* __restrict__ state, int nsteps, int first, int last)
{
    __shared__ __align__(16) float hbuf[2][112];   // 4 slices x 28 (26 used)
    __shared__ __align__(16) float hf32[HID];

    const int b  = blockIdx.x;
    const int t  = threadIdx.x;
    const int jg = t & 3;
    const int nr = t >> 2;                   // 0..111
    const int n  = (nr < HID) ? nr : HID - 1;
    const bool active = (nr < HID);
    const int col  = jg * HID + n;           // owned gate column after transpose
    const int slot = (n / 26) * 28 + (n % 26);

    // U fragments: gate q, 26 j's of slice jg
    float Ur[4][26];
#pragma unroll
    for (int qq = 0; qq < 4; ++qq) {
        const float* up = Ut + (size_t)(qq * HID + n) * 112 + 28 * jg;
#pragma unroll
        for (int r = 0; r < 26; ++r) Ur[qq][r] = up[r];
    }
    const float sbias = bias[col];

    if (t < 112) { hbuf[0][t] = 0.f; hbuf[1][t] = 0.f; }
    float c;
    if (first) {
        c = 0.f;
        __syncthreads();
    } else {
        c = state[BATCH * HID + b * HID + n];      // replicated per quad
        __syncthreads();                           // zeros visible
        if (t < HID) hbuf[0][(t / 26) * 28 + (t % 26)] = state[b * HID + t];
        __syncthreads();
    }

    const float* __restrict__ zp = pre + ((size_t)b * G4 + col) * nsteps;
    float4 zA = *(const float4*)zp;          // steps 0..3
    float4 zB = *(const float4*)(zp + 4);    // steps 4..7

    const float scale = (jg == 2) ? -LOG2E2 : -LOG2E;
    const float Aact  = (jg == 2) ? 2.0f : 1.0f;
    const float Bact  = (jg == 2) ? -1.0f : 0.0f;
    const bool b0 = (jg & 1) != 0, b1 = (jg & 2) != 0;

    float hn_last = 0.f;

    auto step = [&](float zin, int cur) {
        const float* hb = &hbuf[cur][jg * 28];
        float hv[26];
        {
            float4 v0 = *(const float4*)(hb);
            float4 v1 = *(const float4*)(hb + 4);
            float4 v2 = *(const float4*)(hb + 8);
            float4 v3 = *(const float4*)(hb + 12);
            float4 v4 = *(const float4*)(hb + 16);
            float4 v5 = *(const float4*)(hb + 20);
            float2 v6 = *(const float2*)(hb + 24);
            hv[0]=v0.x; hv[1]=v0.y; hv[2]=v0.z; hv[3]=v0.w;
            hv[4]=v1.x; hv[5]=v1.y; hv[6]=v1.z; hv[7]=v1.w;
            hv[8]=v2.x; hv[9]=v2.y; hv[10]=v2.z; hv[11]=v2.w;
            hv[12]=v3.x; hv[13]=v3.y; hv[14]=v3.z; hv[15]=v3.w;
            hv[16]=v4.x; hv[17]=v4.y; hv[18]=v4.z; hv[19]=v4.w;
            hv[20]=v5.x; hv[21]=v5.y; hv[22]=v5.z; hv[23]=v5.w;
            hv[24]=v6.x; hv[25]=v6.y;
        }

        float p0 = 0.f, p1 = 0.f, p2 = 0.f, p3 = 0.f;
#pragma unroll
        for (int r = 0; r < 26; ++r) {
            float hr = hv[r];
            p0 = fmaf(Ur[0][r], hr, p0);
            p1 = fmaf(Ur[1][r], hr, p1);
            p2 = fmaf(Ur[2][r], hr, p2);
            p3 = fmaf(Ur[3][r], hr, p3);
        }

        // quad transpose-reduce: end with full sum of column jg*100+n
        float sA = b0 ? p0 : p1;  float rA = __shfl_xor(sA, 1);
        float sB = b0 ? p2 : p3;  float rB = __shfl_xor(sB, 1);
        float r0 = (b0 ? p1 : p0) + rA;      // gate b0, summed over slice pair
        float r1 = (b0 ? p3 : p2) + rB;      // gate 2+b0
        float sC = b1 ? r0 : r1;  float rC = __shfl_xor(sC, 2);
        float a  = (b1 ? r1 : r0) + rC + zin + sbias;

        float e = __builtin_amdgcn_exp2f(scale * a);
        float v = fmaf(Aact, __builtin_amdgcn_rcpf(1.0f + e), Bact);

        // quad gate-combine (verified rounds 2/3)
        float q1 = __shfl_xor(v, 1);
        float q2 = __shfl_xor(v, 2);
        float q3 = __shfl_xor(q1, 2);
        float xi = b1 ? (b0 ? q3 : q2) : (b0 ? q1 : v);
        float xf = b1 ? (b0 ? q2 : q3) : (b0 ? v  : q1);
        float xg = b1 ? (b0 ? q1 : v ) : (b0 ? q3 : q2);
        float xo = b1 ? (b0 ? v  : q1) : (b0 ? q2 : q3);

        c = fmaf(xf, c, xi * xg);            // replicated per quad
        float ec = __builtin_amdgcn_exp2f(-LOG2E2 * c);
        float tc = fmaf(2.0f, __builtin_amdgcn_rcpf(1.0f + ec), -1.0f);
        float hn = xo * tc;
        if (jg == 0 && active) hbuf[cur ^ 1][slot] = hn;
        hn_last = hn;
        __syncthreads();
    };

    for (int s4 = 0; s4 < nsteps; s4 += 4) {     // nsteps % 4 == 0, >= 8
        float4 zn = zA; zA = zB;
        if (s4 + 8 < nsteps) zB = *(const float4*)(zp + s4 + 8);
        step(zn.x, 0);
        step(zn.y, 1);
        step(zn.z, 0);
        step(zn.w, 1);
    }

    if (last) {
        if (jg == 0 && active) hf32[n] = hn_last;
        __syncthreads();
        if (t < NCLS) {
            float acc2 = bd[t];
            const float4* h4 = (const float4*)hf32;
#pragma unroll 5
            for (int j4 = 0; j4 < 25; ++j4) {
                float4 hv = h4[j4];
                acc2 = fmaf(hv.x, Wd[(size_t)(4 * j4 + 0) * NCLS + t], acc2);
                acc2 = fmaf(hv.y, Wd[(size_t)(4 * j4 + 1) * NCLS + t], acc2);
                acc2 = fmaf(hv.z, Wd[(size_t)(4 * j4 + 2) * NCLS + t], acc2);
                acc2 = fmaf(hv.w, Wd[(size_t)(4 * j4 + 3) * NCLS + t], acc2);
            }
            out[(size_t)b * NCLS + t] = acc2;
        }
    } else {
        if (jg == 0 && active) {
            state[b * HID + n] = hn_last;
            state[BATCH * HID + b * HID + n] = c;
        }
    }
}

// ---------------------------------------------------------------------------
extern "C" void kernel_launch(void* const* d_in, const int* in_sizes, int n_in,
                              void* d_out, int out_size, void* d_ws, size_t ws_size,
                              hipStream_t stream)
{
    const float* x    = (const float*)d_in[0];
    const float* W    = (const float*)d_in[1];
    const float* U    = (const float*)d_in[2];
    const float* bias = (const float*)d_in[3];
    const float* Wd   = (const float*)d_in[4];
    const float* bd   = (const float*)d_in[5];
    float* out = (float*)d_out;

    // ws (dwords): [state 51200][Ut 44800][Wt_bf 38400][pre chunk*256*400]
    const size_t fixed_dw = 51200 + 44800 + 38400;   // 134400
    int chunk = 64;
    if      (ws_size >= (fixed_dw + (size_t)384 * BATCH * G4) * 4) chunk = 384;
    else if (ws_size >= (fixed_dw + (size_t)192 * BATCH * G4) * 4) chunk = 192;
    const int nchunks = S_LEN / chunk;

    unsigned int* wsb = (unsigned int*)d_ws;
    float*          state = (float*)wsb;
    float*          Ut    = (float*)(wsb + 51200);
    unsigned short* Wt    = (unsigned short*)(wsb + 96000);
    float*          pre   = (float*)(wsb + 134400);

    wprep<<<(G4 * DIM + 255) / 256, 256, 0, stream>>>(W, Wt);
    uprep<<<(G4 * 112 + 255) / 256, 256, 0, stream>>>(U, Ut);

    for (int ci = 0; ci < nchunks; ++ci) {
        const int s0 = ci * chunk;
        gemm_pre<<<BATCH * (chunk >> 6), 256, 0, stream>>>(x, Wt, pre, s0, chunk);
        lstm_scan<<<BATCH, 448, 0, stream>>>(pre, Ut, bias, Wd, bd, out, state,
                                             chunk, ci == 0 ? 1 : 0,
                                             ci == nchunks - 1 ? 1 : 0);
    }
}

// Round 7
// 365.393 us; speedup vs baseline: 3.0295x; 1.0573x over previous
//
#include <hip/hip_runtime.h>
#include <cstdint>
#include <cstddef>

#define S_LEN 384
#define BATCH 256
#define DIM   192     // HH*WW
#define HID   100
#define G4    400     // 4*HID
#define NCLS  250

#define LOG2E  1.4426950408889634f
#define LOG2E2 2.8853900817779268f

typedef float    f32x4   __attribute__((ext_vector_type(4)));
typedef short    bf16x8  __attribute__((ext_vector_type(8)));
typedef _Float16 half2_t __attribute__((ext_vector_type(2)));
typedef _Float16 f16x4   __attribute__((ext_vector_type(4)));
typedef _Float16 f16x8   __attribute__((ext_vector_type(8)));

static __device__ __forceinline__ unsigned short f2bf(float f) {
    unsigned u = __float_as_uint(f);
    return (unsigned short)((u + 0x7FFFu + ((u >> 16) & 1u)) >> 16);   // RN
}

// ---------------------------------------------------------------------------
// Prep A: Wt_bf[k=400][d=192] bf16  =  W[d][k] transposed+cast
// ---------------------------------------------------------------------------
__global__ void wprep(const float* __restrict__ W, unsigned short* __restrict__ Wt) {
    int i = blockIdx.x * 256 + threadIdx.x;          // 76800 elements
    if (i >= G4 * DIM) return;
    int k = i / DIM, d = i - k * DIM;
    Wt[i] = f2bf(W[(size_t)d * G4 + k]);
}

// ---------------------------------------------------------------------------
// Prep B: Ut2[col=400][p=52] half2 = (U[2p][col], U[2p+1][col]), j>=100 -> 0
// ---------------------------------------------------------------------------
__global__ void uprep(const float* __restrict__ U, half2_t* __restrict__ Ut2) {
    int i = blockIdx.x * 256 + threadIdx.x;          // 400*52 = 20800
    if (i >= G4 * 52) return;
    int col = i / 52, p = i - col * 52;
    int j0 = 2 * p, j1 = 2 * p + 1;
    half2_t v;
    v.x = (_Float16)(j0 < HID ? U[(size_t)j0 * G4 + col] : 0.0f);
    v.y = (_Float16)(j1 < HID ? U[(size_t)j1 * G4 + col] : 0.0f);
    Ut2[i] = v;
}

// ---------------------------------------------------------------------------
// Kernel 1: bf16 MFMA GEMM  pre[b][k][s] = x[b][s][:].W[:][k] + bias[k] (f16)
//   Block = 256 thr (4 waves) = 64 s-rows of one b, all 400 k, K=192.
//   mfma_f32_16x16x32_bf16 (m89/m92-verified; round-6 uint4 W-staging fix).
//   Round-7: bias folded here (saves 1 VALU/step in scan); pre stored f16
//   (halves gemm WRITE and scan FETCH).
// ---------------------------------------------------------------------------
__global__ __launch_bounds__(256, 2)
void gemm_pre(const float* __restrict__ x, const unsigned short* __restrict__ Wt,
              const float* __restrict__ bias, _Float16* __restrict__ preh,
              int s_start, int chunk)
{
    __shared__ unsigned int xs[64 * 100];    // rows: 200 bf16 (192 + 8 pad)
    __shared__ unsigned int wsh[400 * 20];   // rows: 40 bf16 (32 + 8 pad)

    const int t    = threadIdx.x;
    const int lane = t & 63;
    const int w    = t >> 6;
    const int nsb  = chunk >> 6;
    const int b    = blockIdx.x / nsb;
    const int sblk = blockIdx.x - b * nsb;
    const float* __restrict__ xb = x + ((size_t)b * S_LEN + s_start + sblk * 64) * DIM;

#pragma unroll
    for (int r = 0; r < 12; ++r) {
        int i = t + r * 256;                 // 3072 float4 = 64 rows x 48
        int row = i / 48, c4 = i - row * 48;
        float4 v = ((const float4*)(xb + (size_t)row * DIM))[c4];
        xs[row * 100 + c4 * 2]     = (unsigned)f2bf(v.x) | ((unsigned)f2bf(v.y) << 16);
        xs[row * 100 + c4 * 2 + 1] = (unsigned)f2bf(v.z) | ((unsigned)f2bf(v.w) << 16);
    }

    const int m = lane & 15, q = lane >> 4;

    float bv[25];
#pragma unroll
    for (int ct = 0; ct < 25; ++ct) bv[ct] = bias[ct * 16 + m];

    f32x4 acc[25];
#pragma unroll
    for (int ct = 0; ct < 25; ++ct) acc[ct] = (f32x4){0.f, 0.f, 0.f, 0.f};

    for (int dc = 0; dc < 6; ++dc) {
        if (dc) __syncthreads();             // protect previous chunk's readers
#pragma unroll
        for (int r = 0; r < 7; ++r) {
            int i = t + r * 256;
            if (i < 1600) {                  // 400 rows x 4 uint4 (32 bf16 = 64B)
                int k = i >> 2, u4 = i & 3;
                uint4 v = *(const uint4*)(Wt + (size_t)k * DIM + dc * 32 + u4 * 8);
                *(uint4*)(wsh + k * 20 + u4 * 4) = v;
            }
        }
        __syncthreads();

        const unsigned short* xp = (const unsigned short*)xs
                                   + (16 * w + m) * 200 + dc * 32 + q * 8;
        bf16x8 af = *(const bf16x8*)xp;
#pragma unroll
        for (int ct = 0; ct < 25; ++ct) {
            const unsigned short* bp = (const unsigned short*)wsh
                                       + (ct * 16 + m) * 40 + q * 8;
            bf16x8 bf = *(const bf16x8*)bp;
            acc[ct] = __builtin_amdgcn_mfma_f32_16x16x32_bf16(af, bf, acc[ct], 0, 0, 0);
        }
    }

    // 4 acc regs = 4 consecutive s -> f16x4 (8B) stores, layout [b][k][s]
    _Float16* __restrict__ pb = preh + (size_t)b * G4 * chunk + (size_t)sblk * 64
                                + 16 * w + q * 4;
#pragma unroll
    for (int ct = 0; ct < 25; ++ct) {
        f16x4 v;
        v[0] = (_Float16)(acc[ct][0] + bv[ct]);
        v[1] = (_Float16)(acc[ct][1] + bv[ct]);
        v[2] = (_Float16)(acc[ct][2] + bv[ct]);
        v[3] = (_Float16)(acc[ct][3] + bv[ct]);
        *(f16x4*)(pb + (size_t)(ct * 16 + m) * chunk) = v;
    }
}

// ---------------------------------------------------------------------------
// Kernel 2: LSTM scan, factorized, fdot2 datapath. 448 thr (7 waves) per b.
//   Thread (n = t>>2, jg = t&3):
//     - Uc[4][13] half2 in regs (f16); h slice 26 f16 from LDS (52 B/step)
//     - 52 v_dot2_f32_f16 (fp32 accum) -> 4 partials (round-6: 104 fmaf)
//     - quad transpose-reduce (shfl_xor 1,2, ~6 cndmask) -> own gate's preact
//     - activation; then NO gate-combine selects: v=i, q1=f, q2=g, q3=o on
//       jg=0 (only its c/h are consumed; other lanes compute bounded garbage)
//     - ONE barrier/step. pre stream f16, contiguous in s, 8-step lookahead.
// ---------------------------------------------------------------------------
__global__ __launch_bounds__(448)
void lstm_scan(const _Float16* __restrict__ preh, const half2_t* __restrict__ Ut2,
               const float* __restrict__ Wd, const float* __restrict__ bd,
               float* __restrict__ out, float* __restrict__ state,
               int nsteps, int first, int last)
{
    __shared__ _Float16 h2[2][128];          // 4 slices x 32 f16 (26 used)
    __shared__ __align__(16) float hf32[HID];

    const int b  = blockIdx.x;
    const int t  = threadIdx.x;
    const int jg = t & 3;
    const int nr = t >> 2;                   // 0..111
    const int n  = (nr < HID) ? nr : HID - 1;
    const bool active = (nr < HID);
    const int col  = jg * HID + n;           // owned gate column after transpose
    const int slot = (n / 26) * 32 + (n % 26);

    // U fragments: gate qq, 13 j-pairs of slice jg (j = 26jg .. 26jg+25)
    half2_t Uc[4][13];
#pragma unroll
    for (int qq = 0; qq < 4; ++qq) {
        const half2_t* up = Ut2 + (size_t)(qq * HID + n) * 52 + 13 * jg;
#pragma unroll
        for (int r = 0; r < 13; ++r) Uc[qq][r] = up[r];
    }

    if (t < 128) { h2[0][t] = (_Float16)0.f; h2[1][t] = (_Float16)0.f; }
    float c;
    if (first) {
        c = 0.f;
        __syncthreads();
    } else {
        c = state[BATCH * HID + b * HID + n];     // valid on jg=0 (the consumer)
        __syncthreads();                          // zeros visible
        if (t < HID) h2[0][(t / 26) * 32 + (t % 26)] = (_Float16)state[b * HID + t];
        __syncthreads();
    }

    const _Float16* __restrict__ zp = preh + ((size_t)b * G4 + col) * nsteps;
    f16x4 zA = *(const f16x4*)zp;            // steps 0..3
    f16x4 zB = *(const f16x4*)(zp + 4);      // steps 4..7

    const float scale = (jg == 2) ? -LOG2E2 : -LOG2E;
    const float Aact  = (jg == 2) ? 2.0f : 1.0f;
    const float Bact  = (jg == 2) ? -1.0f : 0.0f;
    const bool b0 = (jg & 1) != 0, b1 = (jg & 2) != 0;

    float hn_last = 0.f;

    auto step = [&](float zin, int cur) {
        const _Float16* hb = &h2[cur][jg * 32];
        f16x8  hA  = *(const f16x8*)hb;            // f16 0..7
        f16x8  hB  = *(const f16x8*)(hb + 8);      // f16 8..15
        f16x8  hC  = *(const f16x8*)(hb + 16);     // f16 16..23
        half2_t hD = *(const half2_t*)(hb + 24);   // f16 24..25
        half2_t hp[13];
        hp[0]  = __builtin_shufflevector(hA, hA, 0, 1);
        hp[1]  = __builtin_shufflevector(hA, hA, 2, 3);
        hp[2]  = __builtin_shufflevector(hA, hA, 4, 5);
        hp[3]  = __builtin_shufflevector(hA, hA, 6, 7);
        hp[4]  = __builtin_shufflevector(hB, hB, 0, 1);
        hp[5]  = __builtin_shufflevector(hB, hB, 2, 3);
        hp[6]  = __builtin_shufflevector(hB, hB, 4, 5);
        hp[7]  = __builtin_shufflevector(hB, hB, 6, 7);
        hp[8]  = __builtin_shufflevector(hC, hC, 0, 1);
        hp[9]  = __builtin_shufflevector(hC, hC, 2, 3);
        hp[10] = __builtin_shufflevector(hC, hC, 4, 5);
        hp[11] = __builtin_shufflevector(hC, hC, 6, 7);
        hp[12] = hD;

        float p0 = 0.f, p1 = 0.f, p2 = 0.f, p3 = 0.f;
#pragma unroll
        for (int r = 0; r < 13; ++r) {
            p0 = __builtin_amdgcn_fdot2(Uc[0][r], hp[r], p0, false);
            p1 = __builtin_amdgcn_fdot2(Uc[1][r], hp[r], p1, false);
            p2 = __builtin_amdgcn_fdot2(Uc[2][r], hp[r], p2, false);
            p3 = __builtin_amdgcn_fdot2(Uc[3][r], hp[r], p3, false);
        }

        // quad transpose-reduce: end with full sum of column jg*100+n
        float sA = b0 ? p0 : p1;  float rA = __shfl_xor(sA, 1);
        float sB = b0 ? p2 : p3;  float rB = __shfl_xor(sB, 1);
        float r0 = (b0 ? p1 : p0) + rA;
        float r1 = (b0 ? p3 : p2) + rB;
        float sC = b1 ? r0 : r1;  float rC = __shfl_xor(sC, 2);
        float a  = (b1 ? r1 : r0) + rC + zin;      // bias already in pre

        float e = __builtin_amdgcn_exp2f(scale * a);
        float v = fmaf(Aact, __builtin_amdgcn_rcpf(1.0f + e), Bact);

        // gather to jg=0 (no selects; only jg=0's result is consumed):
        //   q1 = v(jg^1) = f;  q2 = v(jg^2) = g;  q3 = q1(jg^2) = v(jg3) = o
        float q1 = __shfl_xor(v, 1);
        float q2 = __shfl_xor(v, 2);
        float q3 = __shfl_xor(q1, 2);

        c = fmaf(q1, c, v * q2);             // f*c + i*g   (valid on jg=0)
        float ec = __builtin_amdgcn_exp2f(-LOG2E2 * c);
        float tc = fmaf(2.0f, __builtin_amdgcn_rcpf(1.0f + ec), -1.0f);
        float hn = q3 * tc;                  // o * tanh(c) (valid on jg=0)
        if (jg == 0 && active) h2[cur ^ 1][slot] = (_Float16)hn;
        hn_last = hn;
        __syncthreads();
    };

    for (int s4 = 0; s4 < nsteps; s4 += 4) {     // nsteps % 4 == 0, >= 8
        f16x4 zn = zA; zA = zB;
        if (s4 + 8 < nsteps) zB = *(const f16x4*)(zp + s4 + 8);
        step((float)zn[0], 0);
        step((float)zn[1], 1);
        step((float)zn[2], 0);
        step((float)zn[3], 1);
    }

    if (last) {
        if (jg == 0 && active) hf32[n] = hn_last;
        __syncthreads();
        if (t < NCLS) {
            float acc2 = bd[t];
            const float4* h4 = (const float4*)hf32;
#pragma unroll 5
            for (int j4 = 0; j4 < 25; ++j4) {
                float4 hv = h4[j4];
                acc2 = fmaf(hv.x, Wd[(size_t)(4 * j4 + 0) * NCLS + t], acc2);
                acc2 = fmaf(hv.y, Wd[(size_t)(4 * j4 + 1) * NCLS + t], acc2);
                acc2 = fmaf(hv.z, Wd[(size_t)(4 * j4 + 2) * NCLS + t], acc2);
                acc2 = fmaf(hv.w, Wd[(size_t)(4 * j4 + 3) * NCLS + t], acc2);
            }
            out[(size_t)b * NCLS + t] = acc2;
        }
    } else {
        if (jg == 0 && active) {
            state[b * HID + n] = hn_last;
            state[BATCH * HID + b * HID + n] = c;
        }
    }
}

// ---------------------------------------------------------------------------
extern "C" void kernel_launch(void* const* d_in, const int* in_sizes, int n_in,
                              void* d_out, int out_size, void* d_ws, size_t ws_size,
                              hipStream_t stream)
{
    const float* x    = (const float*)d_in[0];
    const float* W    = (const float*)d_in[1];
    const float* U    = (const float*)d_in[2];
    const float* bias = (const float*)d_in[3];
    const float* Wd   = (const float*)d_in[4];
    const float* bd   = (const float*)d_in[5];
    float* out = (float*)d_out;

    // ws (dwords): [state 51200][Ut2 20800][Wt_bf 38400][preh f16: chunk*51200 dw]
    const size_t fixed_dw = 51200 + 20800 + 38400;   // 110400
    int chunk = 64;
    if      (ws_size >= (fixed_dw + (size_t)384 * 51200) * 4) chunk = 384;
    else if (ws_size >= (fixed_dw + (size_t)192 * 51200) * 4) chunk = 192;
    const int nchunks = S_LEN / chunk;

    unsigned int* wsb = (unsigned int*)d_ws;
    float*          state = (float*)wsb;
    half2_t*        Ut2   = (half2_t*)(wsb + 51200);
    unsigned short* Wt    = (unsigned short*)(wsb + 72000);
    _Float16*       preh  = (_Float16*)(wsb + 110400);

    wprep<<<(G4 * DIM + 255) / 256, 256, 0, stream>>>(W, Wt);
    uprep<<<(G4 * 52 + 255) / 256, 256, 0, stream>>>(U, Ut2);

    for (int ci = 0; ci < nchunks; ++ci) {
        const int s0 = ci * chunk;
        gemm_pre<<<BATCH * (chunk >> 6), 256, 0, stream>>>(x, Wt, bias, preh, s0, chunk);
        lstm_scan<<<BATCH, 448, 0, stream>>>(preh, Ut2, Wd, bd, out, state,
                                             chunk, ci == 0 ? 1 : 0,
                                             ci == nchunks - 1 ? 1 : 0);
    }
}

// Round 8
// 330.223 us; speedup vs baseline: 3.3521x; 1.1065x over previous
//
#include <hip/hip_runtime.h>
#include <cstdint>
#include <cstddef>

#define S_LEN 384
#define BATCH 256
#define DIM   192     // HH*WW
#define HID   100
#define G4    400     // 4*HID
#define NCLS  250

#define LOG2E  1.4426950408889634f
#define LOG2E2 2.8853900817779268f

typedef float    f32x4   __attribute__((ext_vector_type(4)));
typedef short    bf16x8  __attribute__((ext_vector_type(8)));
typedef _Float16 half2_t __attribute__((ext_vector_type(2)));
typedef _Float16 f16x4   __attribute__((ext_vector_type(4)));
typedef _Float16 f16x8   __attribute__((ext_vector_type(8)));

static __device__ __forceinline__ unsigned short f2bf(float f) {
    unsigned u = __float_as_uint(f);
    return (unsigned short)((u + 0x7FFFu + ((u >> 16) & 1u)) >> 16);   // RN
}

// DPP quad_perm cross-lane (VALU, ~2cyc; __shfl_xor lowers to ds_bpermute =
// LDS-pipe latency on the per-step critical path -> round 7's 732cyc stalls)
template<int CTRL>
static __device__ __forceinline__ float fdpp(float x) {
    return __int_as_float(
        __builtin_amdgcn_mov_dpp(__float_as_int(x), CTRL, 0xF, 0xF, true));
}
#define DPP_X1 0xB1   // quad_perm [1,0,3,2]  == xor 1
#define DPP_X2 0x4E   // quad_perm [2,3,0,1]  == xor 2

// ---------------------------------------------------------------------------
// Prep (merged): blocks [0,300): Wt_bf[k=400][d=192] = bf16(W[d][k]);
//                blocks [300,382): Ut2[col=400][p=52] half2 of U^T (pad 0)
// ---------------------------------------------------------------------------
__global__ void prep(const float* __restrict__ W, const float* __restrict__ U,
                     unsigned short* __restrict__ Wt, half2_t* __restrict__ Ut2)
{
    int bid = blockIdx.x;
    if (bid < 300) {
        int i = bid * 256 + threadIdx.x;             // 76800 elements
        if (i >= G4 * DIM) return;
        int k = i / DIM, d = i - k * DIM;
        Wt[i] = f2bf(W[(size_t)d * G4 + k]);
    } else {
        int i = (bid - 300) * 256 + threadIdx.x;     // 400*52 = 20800
        if (i >= G4 * 52) return;
        int col = i / 52, p = i - col * 52;
        int j0 = 2 * p, j1 = 2 * p + 1;
        half2_t v;
        v.x = (_Float16)(j0 < HID ? U[(size_t)j0 * G4 + col] : 0.0f);
        v.y = (_Float16)(j1 < HID ? U[(size_t)j1 * G4 + col] : 0.0f);
        Ut2[i] = v;
    }
}

// ---------------------------------------------------------------------------
// Kernel 1: bf16 MFMA GEMM  pre[b][k][s] = x[b][s][:].W[:][k] + bias[k] (f16)
//   Block = 256 thr (4 waves) = 64 s-rows of one b, all 400 k, K=192.
//   mfma_f32_16x16x32_bf16 (m89/m92-verified; uint4 W-staging).
//   Unchanged from round 7 -- its counters never surfaced; once the scan
//   drops below it, round 9 gets its rocprof row.
// ---------------------------------------------------------------------------
__global__ __launch_bounds__(256, 2)
void gemm_pre(const float* __restrict__ x, const unsigned short* __restrict__ Wt,
              const float* __restrict__ bias, _Float16* __restrict__ preh,
              int s_start, int chunk)
{
    __shared__ unsigned int xs[64 * 100];    // rows: 200 bf16 (192 + 8 pad)
    __shared__ unsigned int wsh[400 * 20];   // rows: 40 bf16 (32 + 8 pad)

    const int t    = threadIdx.x;
    const int lane = t & 63;
    const int w    = t >> 6;
    const int nsb  = chunk >> 6;
    const int b    = blockIdx.x / nsb;
    const int sblk = blockIdx.x - b * nsb;
    const float* __restrict__ xb = x + ((size_t)b * S_LEN + s_start + sblk * 64) * DIM;

#pragma unroll
    for (int r = 0; r < 12; ++r) {
        int i = t + r * 256;                 // 3072 float4 = 64 rows x 48
        int row = i / 48, c4 = i - row * 48;
        float4 v = ((const float4*)(xb + (size_t)row * DIM))[c4];
        xs[row * 100 + c4 * 2]     = (unsigned)f2bf(v.x) | ((unsigned)f2bf(v.y) << 16);
        xs[row * 100 + c4 * 2 + 1] = (unsigned)f2bf(v.z) | ((unsigned)f2bf(v.w) << 16);
    }

    const int m = lane & 15, q = lane >> 4;

    float bv[25];
#pragma unroll
    for (int ct = 0; ct < 25; ++ct) bv[ct] = bias[ct * 16 + m];

    f32x4 acc[25];
#pragma unroll
    for (int ct = 0; ct < 25; ++ct) acc[ct] = (f32x4){0.f, 0.f, 0.f, 0.f};

    for (int dc = 0; dc < 6; ++dc) {
        if (dc) __syncthreads();             // protect previous chunk's readers
#pragma unroll
        for (int r = 0; r < 7; ++r) {
            int i = t + r * 256;
            if (i < 1600) {                  // 400 rows x 4 uint4 (32 bf16 = 64B)
                int k = i >> 2, u4 = i & 3;
                uint4 v = *(const uint4*)(Wt + (size_t)k * DIM + dc * 32 + u4 * 8);
                *(uint4*)(wsh + k * 20 + u4 * 4) = v;
            }
        }
        __syncthreads();

        const unsigned short* xp = (const unsigned short*)xs
                                   + (16 * w + m) * 200 + dc * 32 + q * 8;
        bf16x8 af = *(const bf16x8*)xp;
#pragma unroll
        for (int ct = 0; ct < 25; ++ct) {
            const unsigned short* bp = (const unsigned short*)wsh
                                       + (ct * 16 + m) * 40 + q * 8;
            bf16x8 bf = *(const bf16x8*)bp;
            acc[ct] = __builtin_amdgcn_mfma_f32_16x16x32_bf16(af, bf, acc[ct], 0, 0, 0);
        }
    }

    // 4 acc regs = 4 consecutive s -> f16x4 (8B) stores, layout [b][k][s]
    _Float16* __restrict__ pb = preh + (size_t)b * G4 * chunk + (size_t)sblk * 64
                                + 16 * w + q * 4;
#pragma unroll
    for (int ct = 0; ct < 25; ++ct) {
        f16x4 v;
        v[0] = (_Float16)(acc[ct][0] + bv[ct]);
        v[1] = (_Float16)(acc[ct][1] + bv[ct]);
        v[2] = (_Float16)(acc[ct][2] + bv[ct]);
        v[3] = (_Float16)(acc[ct][3] + bv[ct]);
        *(f16x4*)(pb + (size_t)(ct * 16 + m) * chunk) = v;
    }
}

// ---------------------------------------------------------------------------
// Kernel 2: LSTM scan, factorized fdot2 datapath. 448 thr (7 waves) per b.
//   Round-8 changes vs r7 (217us, 46% VALUBusy, 1.38M LDS conflicts):
//   (a) all 6 cross-lane exchanges are DPP quad_perm (VALU) instead of
//       __shfl_xor (ds_bpermute, LDS-pipe latency on the critical path);
//   (b) h slice stride 32 -> 40 f16 (80B): slices land on bank quads
//       {0-3},{20-23},{8-11},{28-31} -> conflict-free.
// ---------------------------------------------------------------------------
__global__ __launch_bounds__(448)
void lstm_scan(const _Float16* __restrict__ preh, const half2_t* __restrict__ Ut2,
               const float* __restrict__ Wd, const float* __restrict__ bd,
               float* __restrict__ out, float* __restrict__ state,
               int nsteps, int first, int last)
{
    __shared__ _Float16 h2[2][160];          // 4 slices x 40 f16 (26 used)
    __shared__ __align__(16) float hf32[HID];

    const int b  = blockIdx.x;
    const int t  = threadIdx.x;
    const int jg = t & 3;
    const int nr = t >> 2;                   // 0..111
    const int n  = (nr < HID) ? nr : HID - 1;
    const bool active = (nr < HID);
    const int col  = jg * HID + n;           // owned gate column after transpose
    const int slot = (n / 26) * 40 + (n % 26);

    // U fragments: gate qq, 13 j-pairs of slice jg (j = 26jg .. 26jg+25)
    half2_t Uc[4][13];
#pragma unroll
    for (int qq = 0; qq < 4; ++qq) {
        const half2_t* up = Ut2 + (size_t)(qq * HID + n) * 52 + 13 * jg;
#pragma unroll
        for (int r = 0; r < 13; ++r) Uc[qq][r] = up[r];
    }

    if (t < 320) ((_Float16*)h2)[t] = (_Float16)0.f;
    float c;
    if (first) {
        c = 0.f;
        __syncthreads();
    } else {
        c = state[BATCH * HID + b * HID + n];     // valid on jg=0 (the consumer)
        __syncthreads();                          // zeros visible
        if (t < HID) h2[0][(t / 26) * 40 + (t % 26)] = (_Float16)state[b * HID + t];
        __syncthreads();
    }

    const _Float16* __restrict__ zp = preh + ((size_t)b * G4 + col) * nsteps;
    f16x4 zA = *(const f16x4*)zp;            // steps 0..3
    f16x4 zB = *(const f16x4*)(zp + 4);      // steps 4..7

    const float scale = (jg == 2) ? -LOG2E2 : -LOG2E;
    const float Aact  = (jg == 2) ? 2.0f : 1.0f;
    const float Bact  = (jg == 2) ? -1.0f : 0.0f;
    const bool b0 = (jg & 1) != 0, b1 = (jg & 2) != 0;

    float hn_last = 0.f;

    auto step = [&](float zin, int cur) {
        const _Float16* hb = &h2[cur][jg * 40];
        f16x8  hA  = *(const f16x8*)hb;            // f16 0..7
        f16x8  hB  = *(const f16x8*)(hb + 8);      // f16 8..15
        f16x8  hC  = *(const f16x8*)(hb + 16);     // f16 16..23
        half2_t hD = *(const half2_t*)(hb + 24);   // f16 24..25
        half2_t hp[13];
        hp[0]  = __builtin_shufflevector(hA, hA, 0, 1);
        hp[1]  = __builtin_shufflevector(hA, hA, 2, 3);
        hp[2]  = __builtin_shufflevector(hA, hA, 4, 5);
        hp[3]  = __builtin_shufflevector(hA, hA, 6, 7);
        hp[4]  = __builtin_shufflevector(hB, hB, 0, 1);
        hp[5]  = __builtin_shufflevector(hB, hB, 2, 3);
        hp[6]  = __builtin_shufflevector(hB, hB, 4, 5);
        hp[7]  = __builtin_shufflevector(hB, hB, 6, 7);
        hp[8]  = __builtin_shufflevector(hC, hC, 0, 1);
        hp[9]  = __builtin_shufflevector(hC, hC, 2, 3);
        hp[10] = __builtin_shufflevector(hC, hC, 4, 5);
        hp[11] = __builtin_shufflevector(hC, hC, 6, 7);
        hp[12] = hD;

        float p0 = 0.f, p1 = 0.f, p2 = 0.f, p3 = 0.f;
#pragma unroll
        for (int r = 0; r < 13; ++r) {
            p0 = __builtin_amdgcn_fdot2(Uc[0][r], hp[r], p0, false);
            p1 = __builtin_amdgcn_fdot2(Uc[1][r], hp[r], p1, false);
            p2 = __builtin_amdgcn_fdot2(Uc[2][r], hp[r], p2, false);
            p3 = __builtin_amdgcn_fdot2(Uc[3][r], hp[r], p3, false);
        }

        // quad transpose-reduce (DPP): end with full sum of column jg*100+n
        float sA = b0 ? p0 : p1;  float rA = fdpp<DPP_X1>(sA);
        float sB = b0 ? p2 : p3;  float rB = fdpp<DPP_X1>(sB);
        float r0 = (b0 ? p1 : p0) + rA;
        float r1 = (b0 ? p3 : p2) + rB;
        float sC = b1 ? r0 : r1;  float rC = fdpp<DPP_X2>(sC);
        float a  = (b1 ? r1 : r0) + rC + zin;      // bias already in pre

        float e = __builtin_amdgcn_exp2f(scale * a);
        float v = fmaf(Aact, __builtin_amdgcn_rcpf(1.0f + e), Bact);

        // gather to jg=0 (only jg=0's result is consumed):
        //   q1 = v(jg^1) = f;  q2 = v(jg^2) = g;  q3 = v(jg^3) = o
        float q1 = fdpp<DPP_X1>(v);
        float q2 = fdpp<DPP_X2>(v);
        float q3 = fdpp<DPP_X2>(q1);

        c = fmaf(q1, c, v * q2);             // f*c + i*g   (valid on jg=0)
        float ec = __builtin_amdgcn_exp2f(-LOG2E2 * c);
        float tc = fmaf(2.0f, __builtin_amdgcn_rcpf(1.0f + ec), -1.0f);
        float hn = q3 * tc;                  // o * tanh(c) (valid on jg=0)
        if (jg == 0 && active) h2[cur ^ 1][slot] = (_Float16)hn;
        hn_last = hn;
        __syncthreads();
    };

    for (int s4 = 0; s4 < nsteps; s4 += 4) {     // nsteps % 4 == 0, >= 8
        f16x4 zn = zA; zA = zB;
        if (s4 + 8 < nsteps) zB = *(const f16x4*)(zp + s4 + 8);
        step((float)zn[0], 0);
        step((float)zn[1], 1);
        step((float)zn[2], 0);
        step((float)zn[3], 1);
    }

    if (last) {
        if (jg == 0 && active) hf32[n] = hn_last;
        __syncthreads();
        if (t < NCLS) {
            float acc2 = bd[t];
            const float4* h4 = (const float4*)hf32;
#pragma unroll 5
            for (int j4 = 0; j4 < 25; ++j4) {
                float4 hv = h4[j4];
                acc2 = fmaf(hv.x, Wd[(size_t)(4 * j4 + 0) * NCLS + t], acc2);
                acc2 = fmaf(hv.y, Wd[(size_t)(4 * j4 + 1) * NCLS + t], acc2);
                acc2 = fmaf(hv.z, Wd[(size_t)(4 * j4 + 2) * NCLS + t], acc2);
                acc2 = fmaf(hv.w, Wd[(size_t)(4 * j4 + 3) * NCLS + t], acc2);
            }
            out[(size_t)b * NCLS + t] = acc2;
        }
    } else {
        if (jg == 0 && active) {
            state[b * HID + n] = hn_last;
            state[BATCH * HID + b * HID + n] = c;
        }
    }
}

// ---------------------------------------------------------------------------
extern "C" void kernel_launch(void* const* d_in, const int* in_sizes, int n_in,
                              void* d_out, int out_size, void* d_ws, size_t ws_size,
                              hipStream_t stream)
{
    const float* x    = (const float*)d_in[0];
    const float* W    = (const float*)d_in[1];
    const float* U    = (const float*)d_in[2];
    const float* bias = (const float*)d_in[3];
    const float* Wd   = (const float*)d_in[4];
    const float* bd   = (const float*)d_in[5];
    float* out = (float*)d_out;

    // ws (dwords): [state 51200][Ut2 20800][Wt_bf 38400][preh f16: chunk*51200 dw]
    const size_t fixed_dw = 51200 + 20800 + 38400;   // 110400
    int chunk = 64;
    if      (ws_size >= (fixed_dw + (size_t)384 * 51200) * 4) chunk = 384;
    else if (ws_size >= (fixed_dw + (size_t)192 * 51200) * 4) chunk = 192;
    const int nchunks = S_LEN / chunk;

    unsigned int* wsb = (unsigned int*)d_ws;
    float*          state = (float*)wsb;
    half2_t*        Ut2   = (half2_t*)(wsb + 51200);
    unsigned short* Wt    = (unsigned short*)(wsb + 72000);
    _Float16*       preh  = (_Float16*)(wsb + 110400);

    prep<<<382, 256, 0, stream>>>(W, U, Wt, Ut2);

    for (int ci = 0; ci < nchunks; ++ci) {
        const int s0 = ci * chunk;
        gemm_pre<<<BATCH * (chunk >> 6), 256, 0, stream>>>(x, Wt, bias, preh, s0, chunk);
        lstm_scan<<<BATCH, 448, 0, stream>>>(preh, Ut2, Wd, bd, out, state,
                                             chunk, ci == 0 ? 1 : 0,
                                             ci == nchunks - 1 ? 1 : 0);
    }
}